// Round 11
// baseline (249.259 us; speedup 1.0000x reference)
//
#include <hip/hip_runtime.h>

// WaterLevelGCN r25: r24 + (1) gather8 generalized edge-SPLIT: az (F=128)
// goes 2-way/tpn32 -> 4-way/tpn64 (one node/wave, ~8 edges/sub => single
// 8x batch; grid 512->1024), combine via 2-step shfl_xor tree. Association
// change only (r16-proven inert class). (2) w2 K-split z=4->2 + ln nacc=2:
// halves ff2p round-trip (16MB->8MB).
// LESSON (r22): cross-block producer->consumer fusion via threadfence+flag
// is a non-starter on multi-XCD CDNA4 (100us stall; MfmaUtil 0.8%).
// LESSON (r19): fusion that shrinks grid below ~256 blocks or adds
// per-chunk barriers loses more to latency than it saves in traffic.
// LESSON (r10-r12): 48KB-LDS kernels silently never ran; keep LDS <= 44KB.
// Disjoint layout (ws = 256 MiB):
// qkQK@0(2M) Vg@2M(1M) Op@3145728(4x2M) Lp@11534336(4x64K)
// cursor@11796480(16K) dflag@11812864(16K) csr@11829248(2M [4096][128])
// y_f32@13926400(2M) y_bf@16023552(1M) z@17072128(1M) az@18120704(1M)
// h1@19169280(2M) ah1@21266432(2M) h2@23363584(2M) t3@25460736(.5M)
// ff1@25985024(16M) ff2p@42762240(2x2M)

typedef unsigned short u16;
typedef __attribute__((ext_vector_type(8))) short bf16x8;
typedef __attribute__((ext_vector_type(4))) float f32x4;

__device__ __forceinline__ float b2f(u16 u) {
  union { unsigned int i; float f; } x; x.i = ((unsigned int)u) << 16; return x.f;
}
__device__ __forceinline__ u16 f2b(float f) {
  union { float f; unsigned int i; } x; x.f = f;
  unsigned int r = x.i + 0x7FFFu + ((x.i >> 16) & 1u);
  return (u16)(r >> 16);
}
__device__ __forceinline__ float ld1(const void* p, size_t i, int bf) {
  return bf ? b2f(((const u16*)p)[i]) : ((const float*)p)[i];
}

// ------------- GEMM device body (r9/r15-proven math) -----------------------
// flags: 1=relu, 2=acc, 4=C f32, 8=bias, 16=A raw input, 32=K-split f32
//        partial store, 64=A f32 internal (dead), 128=in_proj special.
__device__ void gemm_body(
    int bx, int by, int bz, int nz,
    const void* __restrict__ A, const void* __restrict__ B,
    const void* __restrict__ bias, void* __restrict__ C, void* __restrict__ C2,
    int N, int K, int lda, int ldb, int bRow0, int bK0, int flags,
    const int* __restrict__ dflag, const float* __restrict__ divL)
{
  const int wbf = *dflag;
  const int abf = (flags & 64) ? 0 : ((flags & 16) ? wbf : 1);
  __shared__ u16 As[64][128];
  __shared__ u16 Bs[64][128];
  const int tid = threadIdx.x;
  const int wv = tid >> 6, l = tid & 63;
  const int lr = l & 15, lq = l >> 4;
  const int row0 = by * 64, col0 = bx * 64;
  const int qr = 32 * (wv >> 1), qc = 32 * (wv & 1);
  const int sr = tid >> 2, sb = tid & 3;
  const int Kz = K / nz;
  const int k0 = bz * Kz;
  f32x4 acc[2][2] = {};
  for (int kt = k0; kt < k0 + Kz; kt += 128) {
    __syncthreads();
#pragma unroll
    for (int g = 0; g < 4; g++) {
      int b = sb + 4 * g;
      int cc = b * 8;
      int bs = (b ^ (sr & 15)) * 8;
      size_t offA = (size_t)(row0 + sr) * lda + kt + cc;
      if (abf) {
        *(bf16x8*)&As[sr][bs] = *(const bf16x8*)((const u16*)A + offA);
      } else {
        const float* pf = (const float*)A + offA;
        float iv = divL
            ? 1.0f / divL[(size_t)((kt + cc) >> 5) * 4096 + row0 + sr]
            : 1.0f;
        float4 f0 = *(const float4*)pf, f1 = *(const float4*)(pf + 4);
        u16 t[8] = {f2b(f0.x*iv), f2b(f0.y*iv), f2b(f0.z*iv), f2b(f0.w*iv),
                    f2b(f1.x*iv), f2b(f1.y*iv), f2b(f1.z*iv), f2b(f1.w*iv)};
        *(bf16x8*)&As[sr][bs] = *(bf16x8*)t;
      }
      size_t offB = (size_t)(bRow0 + col0 + sr) * ldb + bK0 + kt + cc;
      if (wbf) {
        *(bf16x8*)&Bs[sr][bs] = *(const bf16x8*)((const u16*)B + offB);
      } else {
        const float* pf = (const float*)B + offB;
        float4 f0 = *(const float4*)pf, f1 = *(const float4*)(pf + 4);
        u16 t[8] = {f2b(f0.x), f2b(f0.y), f2b(f0.z), f2b(f0.w),
                    f2b(f1.x), f2b(f1.y), f2b(f1.z), f2b(f1.w)};
        *(bf16x8*)&Bs[sr][bs] = *(bf16x8*)t;
      }
    }
    __syncthreads();
#pragma unroll
    for (int kk = 0; kk < 4; kk++) {
      int bxs = ((4 * kk + lq) ^ lr) * 8;
      bf16x8 a0 = *(const bf16x8*)&As[qr + lr][bxs];
      bf16x8 a1 = *(const bf16x8*)&As[qr + 16 + lr][bxs];
      bf16x8 b0 = *(const bf16x8*)&Bs[qc + lr][bxs];
      bf16x8 b1 = *(const bf16x8*)&Bs[qc + 16 + lr][bxs];
      acc[0][0] = __builtin_amdgcn_mfma_f32_16x16x32_bf16(a0, b0, acc[0][0], 0, 0, 0);
      acc[0][1] = __builtin_amdgcn_mfma_f32_16x16x32_bf16(a0, b1, acc[0][1], 0, 0, 0);
      acc[1][0] = __builtin_amdgcn_mfma_f32_16x16x32_bf16(a1, b0, acc[1][0], 0, 0, 0);
      acc[1][1] = __builtin_amdgcn_mfma_f32_16x16x32_bf16(a1, b1, acc[1][1], 0, 0, 0);
    }
  }
  if ((flags & 128) && col0 >= 256) {
#pragma unroll
    for (int i = 0; i < 2; i++) {
#pragma unroll
      for (int j = 0; j < 2; j++) {
        int colg = col0 + qc + 16 * j + lr;
        int d = colg - 256;
        int rowbase = row0 + qr + 16 * i + lq * 4;
        float bb = ld1(bias, colg, wbf);
        ushort4 pv = make_ushort4(
            f2b(acc[i][j][0] + bb), f2b(acc[i][j][1] + bb),
            f2b(acc[i][j][2] + bb), f2b(acc[i][j][3] + bb));
        *(ushort4*)((u16*)C2 + (size_t)d * 4096 + rowbase) = pv;
      }
    }
    return;
  }
  const int ldc = (flags & 128) ? 256 : N;
#pragma unroll
  for (int i = 0; i < 2; i++) {
#pragma unroll
    for (int j = 0; j < 2; j++) {
#pragma unroll
      for (int r = 0; r < 4; r++) {
        int row = row0 + qr + 16 * i + lq * 4 + r;
        int col = col0 + qc + 16 * j + lr;
        float v = acc[i][j][r];
        if (flags & 8) v += ld1(bias, bRow0 + col, wbf);
        if (flags & 1) v = fmaxf(v, 0.f);
        size_t idx = (size_t)row * ldc + col;
        if (flags & 32) {
          ((float*)C)[(size_t)bz * 524288 + idx] = v;
        } else if (flags & 4) {
          float* Cf = (float*)C;
          if (flags & 2) v += Cf[idx];
          Cf[idx] = v;
        } else {
          ((u16*)C)[idx] = f2b(v);
        }
      }
    }
  }
}

__global__ __launch_bounds__(256) void gemm_mfma(
    const void* __restrict__ A, const void* __restrict__ B,
    const void* __restrict__ bias, void* __restrict__ C, void* __restrict__ C2,
    int N, int K, int lda, int ldb, int bRow0, int bK0, int flags,
    const int* __restrict__ dflag, const float* __restrict__ divL)
{
  gemm_body(blockIdx.x, blockIdx.y, blockIdx.z, gridDim.z,
            A, B, bias, C, C2, N, K, lda, ldb, bRow0, bK0, flags, dflag, divL);
}

// ------- block 0 = dtype detect; blocks 1..16 = zero cursor ----------------
__global__ __launch_bounds__(256) void det_zero(
    const void* __restrict__ x, int* __restrict__ flag,
    int* __restrict__ cursor)
{
  if (blockIdx.x == 0) {
    __shared__ int cnt;
    if (threadIdx.x == 0) cnt = 0;
    __syncthreads();
    const u16* p = (const u16*)x;
    int c = 0;
    for (int i = threadIdx.x; i < 4096; i += 256) {
      int e = (p[i] >> 7) & 0xFF;
      if (e >= 140) c++;
    }
    atomicAdd(&cnt, c);
    __syncthreads();
    if (threadIdx.x == 0) flag[0] = (cnt < 64) ? 1 : 0;
  } else {
    cursor[(blockIdx.x - 1) * 256 + threadIdx.x] = 0;
  }
}

// -- merged: blocks 0..383 = in_proj GEMM; 384..511 = bucket-CSR fill x4 ----
__global__ __launch_bounds__(256) void csr_inproj(
    const void* __restrict__ xin, const void* __restrict__ W,
    const void* __restrict__ bias, void* __restrict__ qkQK, void* __restrict__ Vg,
    const int* __restrict__ dflag,
    const int* __restrict__ src, const int* __restrict__ dst,
    int* __restrict__ cursor, int* __restrict__ csr, int E)
{
  if (blockIdx.x < 384) {
    gemm_body(blockIdx.x % 6, blockIdx.x / 6, 0, 1,
              xin, W, bias, qkQK, Vg, 384, 128, 128, 128, 0, 0,
              /*bias+Araw+qkv*/ 8 | 16 | 128, dflag, nullptr);
  } else {
    int e0 = ((blockIdx.x - 384) * 256 + threadIdx.x) * 4;
#pragma unroll
    for (int k = 0; k < 4; k++) {
      int e = e0 + k;
      if (e < E) {
        int t = dst[e];
        int pos = atomicAdd(&cursor[t], 1);
        if (pos < 128) csr[(t << 7) + pos] = src[e];  // clamp: OOB hardening
      }
    }
  }
}

// ------ split-K flash attention, fixed-shift softmax, BK=128 (r15) ---------
__global__ __launch_bounds__(256) void attn_part(
    const u16* __restrict__ qk, const u16* __restrict__ Vg,
    float* __restrict__ O, float* __restrict__ L)
{
  const int qt = blockIdx.x, h = blockIdx.y, kc = blockIdx.z;
  const int n0 = qt * 64;
  __shared__ u16 Qs[64][32];
  __shared__ u16 Ks[128][32];
  __shared__ u16 Vt[32][128];
  __shared__ u16 Ps[64][128];
  const int tid = threadIdx.x;
  const int wv = tid >> 6, l = tid & 63;
  const int lr = l & 15, lq = l >> 4;
  const int sr = tid >> 2, sb = tid & 3;
  const int kr = tid >> 1, kb = tid & 1;
  const int vr = tid >> 3, vb = tid & 7;
  *(bf16x8*)&Qs[sr][(sb ^ (sr & 3)) * 8] =
      *(const bf16x8*)(qk + (size_t)(n0 + sr) * 256 + h * 32 + sb * 8);
  __syncthreads();
  const float sc = 0.17677669529663687f;  // 1/sqrt(32), folded into Q frag
  bf16x8 qf;
  {
    bf16x8 qraw = *(const bf16x8*)&Qs[16 * wv + lr][(lq ^ (lr & 3)) * 8];
#pragma unroll
    for (int t = 0; t < 8; t++)
      qf[t] = (short)f2b(b2f((u16)qraw[t]) * sc);
  }
  f32x4 o0 = {}, o1 = {};
  float psum[4] = {0.f, 0.f, 0.f, 0.f};
  for (int t = 0; t < 8; t++) {
    const int m0 = kc * 1024 + t * 128;
    __syncthreads();
#pragma unroll
    for (int cc = 0; cc < 2; cc++) {
      int ch = kb + 2 * cc;
      *(bf16x8*)&Ks[kr][(ch ^ (kr & 3)) * 8] =
          *(const bf16x8*)(qk + (size_t)(m0 + kr) * 256 + 128 + h * 32 + ch * 8);
    }
#pragma unroll
    for (int cc = 0; cc < 2; cc++) {
      int ch = vb + 8 * cc;
      *(bf16x8*)&Vt[vr][(ch ^ (vr & 15)) * 8] =
          *(const bf16x8*)(Vg + (size_t)(h * 32 + vr) * 4096 + m0 + ch * 8);
    }
    __syncthreads();
    f32x4 s[8];
#pragma unroll
    for (int jt = 0; jt < 8; jt++) {
      bf16x8 kf = *(const bf16x8*)&Ks[16 * jt + lr][(lq ^ (lr & 3)) * 8];
      f32x4 z = {};
      s[jt] = __builtin_amdgcn_mfma_f32_16x16x32_bf16(qf, kf, z, 0, 0, 0);
    }
#pragma unroll
    for (int jt = 0; jt < 8; jt++)
#pragma unroll
      for (int r = 0; r < 4; r++) {
        float p = __expf(s[jt][r]);
        psum[r] += p;
        int qrow = 16 * wv + lq * 4 + r;
        int ch = 2 * jt + (lr >> 3);
        Ps[qrow][(ch ^ (qrow & 15)) * 8 + (lr & 7)] = f2b(p);
      }
    __syncthreads();
#pragma unroll
    for (int kk = 0; kk < 4; kk++) {
      int prow = 16 * wv + lr;
      bf16x8 pf = *(const bf16x8*)&Ps[prow][((4 * kk + lq) ^ (lr & 15)) * 8];
      bf16x8 v0 = *(const bf16x8*)&Vt[lr][((4 * kk + lq) ^ (lr & 15)) * 8];
      bf16x8 v1 = *(const bf16x8*)&Vt[16 + lr][((4 * kk + lq) ^ (lr & 15)) * 8];
      o0 = __builtin_amdgcn_mfma_f32_16x16x32_bf16(pf, v0, o0, 0, 0, 0);
      o1 = __builtin_amdgcn_mfma_f32_16x16x32_bf16(pf, v1, o1, 0, 0, 0);
    }
  }
  const size_t ko = (size_t)kc * 524288;
  float* Lk = L + (size_t)kc * 16384;
#pragma unroll
  for (int r = 0; r < 4; r++) {
    int row = n0 + 16 * wv + lq * 4 + r;
    O[ko + (size_t)row * 128 + h * 32 + lr]      = o0[r];
    O[ko + (size_t)row * 128 + h * 32 + 16 + lr] = o1[r];
    float ps = psum[r];
    ps += __shfl_xor(ps, 1); ps += __shfl_xor(ps, 2);
    ps += __shfl_xor(ps, 4); ps += __shfl_xor(ps, 8);
    if (lr == 0) Lk[h * 4096 + row] = ps;
  }
}

// ------- r17: fused out_proj GEMM + residual + LayerNorm1 ------------------
__global__ __launch_bounds__(256) void oproj_ln(
    const float* __restrict__ Op, const float* __restrict__ Lp,
    const void* __restrict__ W, const void* __restrict__ bias,
    const void* __restrict__ x, const void* __restrict__ g,
    const void* __restrict__ bln, u16* __restrict__ y_bf,
    float* __restrict__ y_f32, const int* __restrict__ dflag)
{
  const int wbf = *dflag;
  __shared__ u16 As[16][128];
  __shared__ u16 Bs[128][128];   // re-used as float C[16][128] after MFMA
  const int tid = threadIdx.x;
  const int r0 = blockIdx.x * 16;
  {
    int r = tid >> 4, b = tid & 15;
    int hh = b >> 2;
    float Ls = Lp[hh * 4096 + r0 + r] + Lp[16384 + hh * 4096 + r0 + r]
             + Lp[32768 + hh * 4096 + r0 + r] + Lp[49152 + hh * 4096 + r0 + r];
    float iv = 1.0f / Ls;
    float a8[8] = {};
#pragma unroll
    for (int kc = 0; kc < 4; kc++) {
      const float* p = Op + (size_t)kc * 524288 + (size_t)(r0 + r) * 128 + b * 8;
      float4 q0 = *(const float4*)p, q1 = *(const float4*)(p + 4);
      a8[0] += q0.x; a8[1] += q0.y; a8[2] += q0.z; a8[3] += q0.w;
      a8[4] += q1.x; a8[5] += q1.y; a8[6] += q1.z; a8[7] += q1.w;
    }
    u16 t[8];
#pragma unroll
    for (int j = 0; j < 8; j++) t[j] = f2b(a8[j] * iv);
    *(bf16x8*)&As[r][(b ^ r) * 8] = *(bf16x8*)t;
  }
  {
    int o = tid >> 1, half = tid & 1;
#pragma unroll
    for (int bb8 = 0; bb8 < 8; bb8++) {
      int b = half * 8 + bb8;
      size_t off = (size_t)o * 128 + b * 8;
      if (wbf) {
        *(bf16x8*)&Bs[o][(b ^ (o & 15)) * 8] = *(const bf16x8*)((const u16*)W + off);
      } else {
        const float* pf = (const float*)W + off;
        float4 f0 = *(const float4*)pf, f1 = *(const float4*)(pf + 4);
        u16 t[8] = {f2b(f0.x), f2b(f0.y), f2b(f0.z), f2b(f0.w),
                    f2b(f1.x), f2b(f1.y), f2b(f1.z), f2b(f1.w)};
        *(bf16x8*)&Bs[o][(b ^ (o & 15)) * 8] = *(bf16x8*)t;
      }
    }
  }
  __syncthreads();
  const int wv = tid >> 6, l = tid & 63;
  const int lr = l & 15, lq = l >> 4;
  const int c0 = 32 * wv;
  f32x4 acc[2] = {};
#pragma unroll
  for (int kk = 0; kk < 4; kk++) {
    int bxs = ((4 * kk + lq) ^ lr) * 8;
    bf16x8 a0 = *(const bf16x8*)&As[lr][bxs];
    bf16x8 b0 = *(const bf16x8*)&Bs[c0 + lr][bxs];
    bf16x8 b1 = *(const bf16x8*)&Bs[c0 + 16 + lr][bxs];
    acc[0] = __builtin_amdgcn_mfma_f32_16x16x32_bf16(a0, b0, acc[0], 0, 0, 0);
    acc[1] = __builtin_amdgcn_mfma_f32_16x16x32_bf16(a0, b1, acc[1], 0, 0, 0);
  }
  __syncthreads();  // all LDS reads done; overlay C on Bs
  float* Cf = (float*)&Bs[0][0];
#pragma unroll
  for (int j = 0; j < 2; j++)
#pragma unroll
    for (int r = 0; r < 4; r++) {
      int row = lq * 4 + r, col = c0 + 16 * j + lr;
      float v = acc[j][r] + ld1(bias, col, wbf)
              + ld1(x, (size_t)(r0 + row) * 128 + col, wbf);
      Cf[row * 128 + col] = v;
    }
  __syncthreads();
#pragma unroll
  for (int it = 0; it < 4; it++) {
    int row = it * 4 + wv;
    float v0 = Cf[row * 128 + l], v1 = Cf[row * 128 + 64 + l];
    float s = v0 + v1, sq = v0 * v0 + v1 * v1;
    for (int off = 32; off; off >>= 1) { s += __shfl_down(s, off); sq += __shfl_down(sq, off); }
    s = __shfl(s, 0); sq = __shfl(sq, 0);
    float mu = s * (1.f / 128.f);
    float var = sq * (1.f / 128.f) - mu * mu;
    float rs = rsqrtf(var + 1e-5f);
    float o0 = (v0 - mu) * rs * ld1(g, l, wbf) + ld1(bln, l, wbf);
    float o1 = (v1 - mu) * rs * ld1(g, l + 64, wbf) + ld1(bln, l + 64, wbf);
    size_t i0 = (size_t)(r0 + row) * 128 + l;
    y_bf[i0] = f2b(o0); y_bf[i0 + 64] = f2b(o1);
    y_f32[i0] = o0; y_f32[i0 + 64] = o1;
  }
}

// ------- LayerNorm(A + sum_z R_z (+ rbias[col]))*g + b ---------------------
// float2-vectorized loads (adjacent cols per lane), ushort2 store.
__global__ __launch_bounds__(256) void ln_res(
    const float* __restrict__ A, const float* __restrict__ R,
    int nacc, const void* __restrict__ rbias,
    const void* __restrict__ g, const void* __restrict__ b,
    u16* __restrict__ out_bf, const int* __restrict__ dflag)
{
  const int wbf = *dflag;
  int row = blockIdx.x * 4 + (threadIdx.x >> 6);
  int lane = threadIdx.x & 63;
  size_t base = (size_t)row * 128 + 2 * lane;
  float2 av = *(const float2*)(A + base);
  float v0 = av.x, v1 = av.y;
  for (int z = 0; z < nacc; z++) {
    float2 rv = *(const float2*)(R + (size_t)z * 524288 + base);
    v0 += rv.x; v1 += rv.y;
  }
  if (rbias) { v0 += ld1(rbias, 2 * lane, wbf); v1 += ld1(rbias, 2 * lane + 1, wbf); }
  float s = v0 + v1, sq = v0 * v0 + v1 * v1;
  for (int off = 32; off; off >>= 1) { s += __shfl_down(s, off); sq += __shfl_down(sq, off); }
  s = __shfl(s, 0); sq = __shfl(sq, 0);
  float mu = s * (1.f / 128.f);
  float var = sq * (1.f / 128.f) - mu * mu;
  float rs = rsqrtf(var + 1e-5f);
  float r0 = (v0 - mu) * rs * ld1(g, 2 * lane, wbf) + ld1(b, 2 * lane, wbf);
  float r1 = (v1 - mu) * rs * ld1(g, 2 * lane + 1, wbf) + ld1(b, 2 * lane + 1, wbf);
  *(ushort2*)(out_bf + base) = make_ushort2(f2b(r0), f2b(r1));
}

// -- r25 gather: generalized SPLIT-way edge split, 8x-unrolled, tpn=ft*SPLIT
// az: F=128 SPLIT=4 (one node/wave, ~8 edges/sub); h1: F=256 SPLIT=2.
// Combine = shfl_xor tree over sub axis (association change; inert class).
__global__ __launch_bounds__(256) void gcn_gather8(
    const u16* __restrict__ h, const int* __restrict__ deg,
    const int* __restrict__ csr, u16* __restrict__ out, int F, int SPLIT)
{
  const int ft = F >> 3;           // feature lanes per node (16 or 32)
  const int tpn = ft * SPLIT;      // 64 for both configs
  const int node = blockIdx.x * (256 / tpn) + threadIdx.x / tpn;
  const int wl = threadIdx.x & 63;
  const int gl = threadIdx.x % tpn;
  const int sub = gl / ft;
  const int f = (gl % ft) * 8;
  const int gbase = wl - gl;
  int dn = deg[node]; if (dn > 128) dn = 128;
  float di = rsqrtf((float)(dn + 1));
  float a[8] = {};
  if (sub == 0) {
    bf16x8 hv = *(const bf16x8*)(h + (size_t)node * F + f);
#pragma unroll
    for (int j = 0; j < 8; j++) a[j] = di * b2f((u16)hv[j]);
  }
  const int e0 = node << 7;
  for (int base = 0; base < dn; base += tpn) {
    int lim = dn - base; if (lim > tpn) lim = tpn;
    int mi = 0;
    if (gl < lim) mi = csr[e0 + base + gl];
    float mds = rsqrtf((float)(deg[mi] + 1));
    int nj = (lim - sub + SPLIT - 1) / SPLIT;      // this sub's edge count
    int njmax = (lim + SPLIT - 1) / SPLIT;         // uniform trip count
    for (int jj = 0; jj < njmax; jj += 8) {
      int si[8]; float ds[8]; bool pr[8];
      bf16x8 sv[8];
#pragma unroll
      for (int k = 0; k < 8; k++) {
        int lidx = SPLIT * (jj + k) + sub;         // <= tpn-1 by construction
        si[k] = __shfl(mi, gbase + (lidx & (tpn - 1)));
        ds[k] = __shfl(mds, gbase + (lidx & (tpn - 1)));
        pr[k] = (jj + k < nj);
      }
#pragma unroll
      for (int k = 0; k < 8; k++)
        if (pr[k]) sv[k] = *(const bf16x8*)(h + (size_t)si[k] * F + f);
#pragma unroll
      for (int k = 0; k < 8; k++)
        if (pr[k]) {
#pragma unroll
          for (int j = 0; j < 8; j++) a[j] += ds[k] * b2f((u16)sv[k][j]);
        }
    }
  }
  for (int m = ft; m < tpn; m <<= 1) {
#pragma unroll
    for (int j = 0; j < 8; j++) a[j] += __shfl_xor(a[j], m);
  }
  if (sub) return;
  u16 t[8];
#pragma unroll
  for (int j = 0; j < 8; j++) t[j] = f2b(a[j] * di);
  *(bf16x8*)(out + (size_t)node * F + f) = *(bf16x8*)t;
}

// -------- final gather (F=64): serial order preserved, 4x-unrolled ---------
__global__ __launch_bounds__(256) void gcn_gather(
    const u16* __restrict__ h, const int* __restrict__ deg,
    const int* __restrict__ csr,
    const void* __restrict__ bias, void* __restrict__ out,
    int F, const int* __restrict__ dflag)
{
  const int wbf = *dflag;
  const int tpn = F >> 2;          // 16
  const int node = blockIdx.x * (256 / tpn) + threadIdx.x / tpn;
  const int wl = threadIdx.x & 63;
  const int gl = threadIdx.x % tpn;
  const int f = gl * 4;
  const int gbase = wl - gl;
  int dn = deg[node]; if (dn > 128) dn = 128;
  float di = rsqrtf((float)(dn + 1));
  ushort4 hv = *(const ushort4*)(h + (size_t)node * F + f);
  float a0 = di * b2f(hv.x), a1 = di * b2f(hv.y);
  float a2 = di * b2f(hv.z), a3 = di * b2f(hv.w);
  const int e0 = node << 7;
  for (int base = 0; base < dn; base += tpn) {
    int lim = dn - base; if (lim > tpn) lim = tpn;
    int mi = 0;
    if (gl < lim) mi = csr[e0 + base + gl];
    float mds = rsqrtf((float)(deg[mi] + 1));
    for (int j = 0; j < lim; j += 4) {
      int s0 = __shfl(mi, gbase + j);
      float d0 = __shfl(mds, gbase + j);
      int s1 = __shfl(mi, gbase + j + 1);   // wraps if OOR; unused
      float d1 = __shfl(mds, gbase + j + 1);
      int s2 = __shfl(mi, gbase + j + 2);
      float d2 = __shfl(mds, gbase + j + 2);
      int s3 = __shfl(mi, gbase + j + 3);
      float d3 = __shfl(mds, gbase + j + 3);
      bool p1 = (j + 1 < lim), p2 = (j + 2 < lim), p3 = (j + 3 < lim);
      ushort4 sv0 = *(const ushort4*)(h + (size_t)s0 * F + f);
      ushort4 sv1, sv2, sv3;
      if (p1) sv1 = *(const ushort4*)(h + (size_t)s1 * F + f);
      if (p2) sv2 = *(const ushort4*)(h + (size_t)s2 * F + f);
      if (p3) sv3 = *(const ushort4*)(h + (size_t)s3 * F + f);
      a0 += d0 * b2f(sv0.x); a1 += d0 * b2f(sv0.y);
      a2 += d0 * b2f(sv0.z); a3 += d0 * b2f(sv0.w);
      if (p1) {
        a0 += d1 * b2f(sv1.x); a1 += d1 * b2f(sv1.y);
        a2 += d1 * b2f(sv1.z); a3 += d1 * b2f(sv1.w);
      }
      if (p2) {
        a0 += d2 * b2f(sv2.x); a1 += d2 * b2f(sv2.y);
        a2 += d2 * b2f(sv2.z); a3 += d2 * b2f(sv2.w);
      }
      if (p3) {
        a0 += d3 * b2f(sv3.x); a1 += d3 * b2f(sv3.y);
        a2 += d3 * b2f(sv3.z); a3 += d3 * b2f(sv3.w);
      }
    }
  }
  float b0 = bias ? ld1(bias, f, wbf)     : 0.f;
  float b1 = bias ? ld1(bias, f + 1, wbf) : 0.f;
  float b2 = bias ? ld1(bias, f + 2, wbf) : 0.f;
  float b3 = bias ? ld1(bias, f + 3, wbf) : 0.f;
  float v0 = a0 * di + b0, v1 = a1 * di + b1;
  float v2 = a2 * di + b2, v3 = a3 * di + b3;
  size_t idx = (size_t)node * F + f;
  if (wbf) {
    *(ushort4*)((u16*)out + idx) = make_ushort4(f2b(v0), f2b(v1), f2b(v2), f2b(v3));
  } else {
    *(float4*)((float*)out + idx) = make_float4(v0, v1, v2, v3);
  }
}

extern "C" void kernel_launch(void* const* d_in, const int* in_sizes, int n_in,
                              void* d_out, int out_size, void* d_ws, size_t ws_size,
                              hipStream_t stream)
{
  const void* x          = d_in[0];
  const int*  edge       = (const int*)d_in[1];
  const void* in_proj_w  = d_in[2];
  const void* in_proj_b  = d_in[3];
  const void* out_proj_w = d_in[4];
  const void* out_proj_b = d_in[5];
  const void* ln1_g      = d_in[6];
  const void* ln1_b      = d_in[7];
  const void* ffn_w1     = d_in[8];
  const void* ffn_b1     = d_in[9];
  const void* ffn_w2     = d_in[10];
  const void* ffn_b2     = d_in[11];
  const void* ln2_g      = d_in[12];
  const void* ln2_b      = d_in[13];
  const void* g1w        = d_in[14];
  const void* g1b        = d_in[15];
  const void* g2w        = d_in[16];
  const void* g2b        = d_in[17];
  const void* g3w        = d_in[18];
  const void* g3b        = d_in[19];
  const int E = in_sizes[1] / 2;
  const int* esrc = edge;
  const int* edst = edge + E;

  char* wsb     = (char*)d_ws;
  u16*   qkQK   = (u16*)(wsb + 0);          // 2 MB
  u16*   Vg     = (u16*)(wsb + 2097152);    // 1 MB
  float* Op     = (float*)(wsb + 3145728);  // 4 x 2 MB partial O
  float* Lp     = (float*)(wsb + 11534336); // 4 x 64 KB partial L
  int*   cursor = (int*)(wsb + 11796480);   // 16 KB (zeroed by det_zero)
  int*   dflag  = (int*)(wsb + 11812864);   // 16 KB slot
  int*   csr    = (int*)(wsb + 11829248);   // 2 MB bucket [4096][128]
  float* y_f32  = (float*)(wsb + 13926400); // 2 MB
  u16*   y_bf   = (u16*)(wsb + 16023552);   // 1 MB
  u16*   z_bf   = (u16*)(wsb + 17072128);   // 1 MB
  u16*   az     = (u16*)(wsb + 18120704);   // 1 MB
  u16*   h1     = (u16*)(wsb + 19169280);   // 2 MB
  u16*   ah1    = (u16*)(wsb + 21266432);   // 2 MB
  u16*   h2     = (u16*)(wsb + 23363584);   // 2 MB
  u16*   t3     = (u16*)(wsb + 25460736);   // 512 KB
  u16*   ff1    = (u16*)(wsb + 25985024);   // 16 MB [4096][2048]
  float* ff2p   = (float*)(wsb + 42762240); // 2 x 2 MB partial

  det_zero<<<17, 256, 0, stream>>>(x, dflag, cursor);
  csr_inproj<<<512, 256, 0, stream>>>(x, in_proj_w, in_proj_b, qkQK, Vg, dflag,
      esrc, edst, cursor, csr, E);

  attn_part<<<dim3(64, 4, 4), 256, 0, stream>>>(qkQK, Vg, Op, Lp);
  oproj_ln<<<256, 256, 0, stream>>>(Op, Lp, out_proj_w, out_proj_b, x,
      ln1_g, ln1_b, y_bf, y_f32, dflag);
  // FFN: w1 (2048 blk), K-split w2 z=2 partial store, ln2 (nacc=2)
  gemm_mfma<<<dim3(32, 64), 256, 0, stream>>>(y_bf, ffn_w1, ffn_b1, ff1, nullptr,
      2048, 128, 128, 128, 0, 0, /*relu+bias*/ 1 | 8, dflag, nullptr);
  gemm_mfma<<<dim3(2, 64, 2), 256, 0, stream>>>(ff1, ffn_w2, nullptr, ff2p, nullptr,
      128, 2048, 2048, 2048, 0, 0, /*K-split partial*/ 32, dflag, nullptr);
  ln_res<<<1024, 256, 0, stream>>>(y_f32, ff2p, 2, ffn_b2, ln2_g, ln2_b,
      z_bf, dflag);

  // 3-layer GCN; aggregation commutes with the weight multiply
  gcn_gather8<<<1024, 256, 0, stream>>>(z_bf, cursor, csr, az, 128, 4);
  gemm_mfma<<<dim3(4, 64), 256, 0, stream>>>(az, g1w, g1b, h1, nullptr,
      256, 128, 128, 128, 0, 0, /*relu+bias*/ 1 | 8, dflag, nullptr);
  gcn_gather8<<<1024, 256, 0, stream>>>(h1, cursor, csr, ah1, 256, 2);
  gemm_mfma<<<dim3(4, 64), 256, 0, stream>>>(ah1, g2w, g2b, h2, nullptr,
      256, 256, 256, 256, 0, 0, /*relu+bias*/ 1 | 8, dflag, nullptr);
  gemm_mfma<<<dim3(1, 64), 256, 0, stream>>>(h2, g3w, nullptr, t3, nullptr,
      64, 256, 256, 256, 0, 0, 0, dflag, nullptr);
  gcn_gather<<<256, 256, 0, stream>>>(t3, cursor, csr, g3b, d_out, 64, dflag);
}

// Round 12
// 242.072 us; speedup vs baseline: 1.0297x; 1.0297x over previous
//
#include <hip/hip_runtime.h>

// WaterLevelGCN r26 == r24 verbatim (best measured: 243.2us). r25's two
// changes both regressed (+6us): SPLIT=4 gather (extra shfl machinery,
// masked trips > MLP gain at deg~32) and w2 z=2 (256 blk = 1/CU occupancy
// loss) — both mini-violations of the r19 lesson. Reverted.
// FLOOR RATIONALE: 13 strictly-dependent dispatches, each < 43us; all
// structural escapes measured-negative on MI355X:
//   r19: sub-256-blk fusion -> 60us barrier-bound kernel (MfmaUtil 2.3%)
//   r22: cross-block threadfence fusion -> 100us XCD-writeback stall
//   r25: parallelism-narrowing micro-splits -> +6us
// Trajectory: 295.4 -> 269.3 -> 259.1 -> 252.4 -> 246.8 -> 243.9 -> 243.2.
// LESSON (r10-r12): 48KB-LDS kernels silently never ran; keep LDS <= 44KB.
// Disjoint layout (ws = 256 MiB):
// qkQK@0(2M) Vg@2M(1M) Op@3145728(4x2M) Lp@11534336(4x64K)
// cursor@11796480(16K) dflag@11812864(16K) csr@11829248(2M [4096][128])
// y_f32@13926400(2M) y_bf@16023552(1M) z@17072128(1M) az@18120704(1M)
// h1@19169280(2M) ah1@21266432(2M) h2@23363584(2M) t3@25460736(.5M)
// ff1@25985024(16M) ff2p@42762240(4x2M)

typedef unsigned short u16;
typedef __attribute__((ext_vector_type(8))) short bf16x8;
typedef __attribute__((ext_vector_type(4))) float f32x4;

__device__ __forceinline__ float b2f(u16 u) {
  union { unsigned int i; float f; } x; x.i = ((unsigned int)u) << 16; return x.f;
}
__device__ __forceinline__ u16 f2b(float f) {
  union { float f; unsigned int i; } x; x.f = f;
  unsigned int r = x.i + 0x7FFFu + ((x.i >> 16) & 1u);
  return (u16)(r >> 16);
}
__device__ __forceinline__ float ld1(const void* p, size_t i, int bf) {
  return bf ? b2f(((const u16*)p)[i]) : ((const float*)p)[i];
}

// ------------- GEMM device body (r9/r15-proven math) -----------------------
// flags: 1=relu, 2=acc, 4=C f32, 8=bias, 16=A raw input, 32=K-split f32
//        partial store, 64=A f32 internal (dead), 128=in_proj special.
__device__ void gemm_body(
    int bx, int by, int bz, int nz,
    const void* __restrict__ A, const void* __restrict__ B,
    const void* __restrict__ bias, void* __restrict__ C, void* __restrict__ C2,
    int N, int K, int lda, int ldb, int bRow0, int bK0, int flags,
    const int* __restrict__ dflag, const float* __restrict__ divL)
{
  const int wbf = *dflag;
  const int abf = (flags & 64) ? 0 : ((flags & 16) ? wbf : 1);
  __shared__ u16 As[64][128];
  __shared__ u16 Bs[64][128];
  const int tid = threadIdx.x;
  const int wv = tid >> 6, l = tid & 63;
  const int lr = l & 15, lq = l >> 4;
  const int row0 = by * 64, col0 = bx * 64;
  const int qr = 32 * (wv >> 1), qc = 32 * (wv & 1);
  const int sr = tid >> 2, sb = tid & 3;
  const int Kz = K / nz;
  const int k0 = bz * Kz;
  f32x4 acc[2][2] = {};
  for (int kt = k0; kt < k0 + Kz; kt += 128) {
    __syncthreads();
#pragma unroll
    for (int g = 0; g < 4; g++) {
      int b = sb + 4 * g;
      int cc = b * 8;
      int bs = (b ^ (sr & 15)) * 8;
      size_t offA = (size_t)(row0 + sr) * lda + kt + cc;
      if (abf) {
        *(bf16x8*)&As[sr][bs] = *(const bf16x8*)((const u16*)A + offA);
      } else {
        const float* pf = (const float*)A + offA;
        float iv = divL
            ? 1.0f / divL[(size_t)((kt + cc) >> 5) * 4096 + row0 + sr]
            : 1.0f;
        float4 f0 = *(const float4*)pf, f1 = *(const float4*)(pf + 4);
        u16 t[8] = {f2b(f0.x*iv), f2b(f0.y*iv), f2b(f0.z*iv), f2b(f0.w*iv),
                    f2b(f1.x*iv), f2b(f1.y*iv), f2b(f1.z*iv), f2b(f1.w*iv)};
        *(bf16x8*)&As[sr][bs] = *(bf16x8*)t;
      }
      size_t offB = (size_t)(bRow0 + col0 + sr) * ldb + bK0 + kt + cc;
      if (wbf) {
        *(bf16x8*)&Bs[sr][bs] = *(const bf16x8*)((const u16*)B + offB);
      } else {
        const float* pf = (const float*)B + offB;
        float4 f0 = *(const float4*)pf, f1 = *(const float4*)(pf + 4);
        u16 t[8] = {f2b(f0.x), f2b(f0.y), f2b(f0.z), f2b(f0.w),
                    f2b(f1.x), f2b(f1.y), f2b(f1.z), f2b(f1.w)};
        *(bf16x8*)&Bs[sr][bs] = *(bf16x8*)t;
      }
    }
    __syncthreads();
#pragma unroll
    for (int kk = 0; kk < 4; kk++) {
      int bxs = ((4 * kk + lq) ^ lr) * 8;
      bf16x8 a0 = *(const bf16x8*)&As[qr + lr][bxs];
      bf16x8 a1 = *(const bf16x8*)&As[qr + 16 + lr][bxs];
      bf16x8 b0 = *(const bf16x8*)&Bs[qc + lr][bxs];
      bf16x8 b1 = *(const bf16x8*)&Bs[qc + 16 + lr][bxs];
      acc[0][0] = __builtin_amdgcn_mfma_f32_16x16x32_bf16(a0, b0, acc[0][0], 0, 0, 0);
      acc[0][1] = __builtin_amdgcn_mfma_f32_16x16x32_bf16(a0, b1, acc[0][1], 0, 0, 0);
      acc[1][0] = __builtin_amdgcn_mfma_f32_16x16x32_bf16(a1, b0, acc[1][0], 0, 0, 0);
      acc[1][1] = __builtin_amdgcn_mfma_f32_16x16x32_bf16(a1, b1, acc[1][1], 0, 0, 0);
    }
  }
  if ((flags & 128) && col0 >= 256) {
#pragma unroll
    for (int i = 0; i < 2; i++) {
#pragma unroll
      for (int j = 0; j < 2; j++) {
        int colg = col0 + qc + 16 * j + lr;
        int d = colg - 256;
        int rowbase = row0 + qr + 16 * i + lq * 4;
        float bb = ld1(bias, colg, wbf);
        ushort4 pv = make_ushort4(
            f2b(acc[i][j][0] + bb), f2b(acc[i][j][1] + bb),
            f2b(acc[i][j][2] + bb), f2b(acc[i][j][3] + bb));
        *(ushort4*)((u16*)C2 + (size_t)d * 4096 + rowbase) = pv;
      }
    }
    return;
  }
  const int ldc = (flags & 128) ? 256 : N;
#pragma unroll
  for (int i = 0; i < 2; i++) {
#pragma unroll
    for (int j = 0; j < 2; j++) {
#pragma unroll
      for (int r = 0; r < 4; r++) {
        int row = row0 + qr + 16 * i + lq * 4 + r;
        int col = col0 + qc + 16 * j + lr;
        float v = acc[i][j][r];
        if (flags & 8) v += ld1(bias, bRow0 + col, wbf);
        if (flags & 1) v = fmaxf(v, 0.f);
        size_t idx = (size_t)row * ldc + col;
        if (flags & 32) {
          ((float*)C)[(size_t)bz * 524288 + idx] = v;
        } else if (flags & 4) {
          float* Cf = (float*)C;
          if (flags & 2) v += Cf[idx];
          Cf[idx] = v;
        } else {
          ((u16*)C)[idx] = f2b(v);
        }
      }
    }
  }
}

__global__ __launch_bounds__(256) void gemm_mfma(
    const void* __restrict__ A, const void* __restrict__ B,
    const void* __restrict__ bias, void* __restrict__ C, void* __restrict__ C2,
    int N, int K, int lda, int ldb, int bRow0, int bK0, int flags,
    const int* __restrict__ dflag, const float* __restrict__ divL)
{
  gemm_body(blockIdx.x, blockIdx.y, blockIdx.z, gridDim.z,
            A, B, bias, C, C2, N, K, lda, ldb, bRow0, bK0, flags, dflag, divL);
}

// ------- block 0 = dtype detect; blocks 1..16 = zero cursor ----------------
__global__ __launch_bounds__(256) void det_zero(
    const void* __restrict__ x, int* __restrict__ flag,
    int* __restrict__ cursor)
{
  if (blockIdx.x == 0) {
    __shared__ int cnt;
    if (threadIdx.x == 0) cnt = 0;
    __syncthreads();
    const u16* p = (const u16*)x;
    int c = 0;
    for (int i = threadIdx.x; i < 4096; i += 256) {
      int e = (p[i] >> 7) & 0xFF;
      if (e >= 140) c++;
    }
    atomicAdd(&cnt, c);
    __syncthreads();
    if (threadIdx.x == 0) flag[0] = (cnt < 64) ? 1 : 0;
  } else {
    cursor[(blockIdx.x - 1) * 256 + threadIdx.x] = 0;
  }
}

// -- merged: blocks 0..383 = in_proj GEMM; 384..511 = bucket-CSR fill x4 ----
__global__ __launch_bounds__(256) void csr_inproj(
    const void* __restrict__ xin, const void* __restrict__ W,
    const void* __restrict__ bias, void* __restrict__ qkQK, void* __restrict__ Vg,
    const int* __restrict__ dflag,
    const int* __restrict__ src, const int* __restrict__ dst,
    int* __restrict__ cursor, int* __restrict__ csr, int E)
{
  if (blockIdx.x < 384) {
    gemm_body(blockIdx.x % 6, blockIdx.x / 6, 0, 1,
              xin, W, bias, qkQK, Vg, 384, 128, 128, 128, 0, 0,
              /*bias+Araw+qkv*/ 8 | 16 | 128, dflag, nullptr);
  } else {
    int e0 = ((blockIdx.x - 384) * 256 + threadIdx.x) * 4;
#pragma unroll
    for (int k = 0; k < 4; k++) {
      int e = e0 + k;
      if (e < E) {
        int t = dst[e];
        int pos = atomicAdd(&cursor[t], 1);
        if (pos < 128) csr[(t << 7) + pos] = src[e];  // clamp: OOB hardening
      }
    }
  }
}

// ------ split-K flash attention, fixed-shift softmax, BK=128 (r15) ---------
__global__ __launch_bounds__(256) void attn_part(
    const u16* __restrict__ qk, const u16* __restrict__ Vg,
    float* __restrict__ O, float* __restrict__ L)
{
  const int qt = blockIdx.x, h = blockIdx.y, kc = blockIdx.z;
  const int n0 = qt * 64;
  __shared__ u16 Qs[64][32];
  __shared__ u16 Ks[128][32];
  __shared__ u16 Vt[32][128];
  __shared__ u16 Ps[64][128];
  const int tid = threadIdx.x;
  const int wv = tid >> 6, l = tid & 63;
  const int lr = l & 15, lq = l >> 4;
  const int sr = tid >> 2, sb = tid & 3;
  const int kr = tid >> 1, kb = tid & 1;
  const int vr = tid >> 3, vb = tid & 7;
  *(bf16x8*)&Qs[sr][(sb ^ (sr & 3)) * 8] =
      *(const bf16x8*)(qk + (size_t)(n0 + sr) * 256 + h * 32 + sb * 8);
  __syncthreads();
  const float sc = 0.17677669529663687f;  // 1/sqrt(32), folded into Q frag
  bf16x8 qf;
  {
    bf16x8 qraw = *(const bf16x8*)&Qs[16 * wv + lr][(lq ^ (lr & 3)) * 8];
#pragma unroll
    for (int t = 0; t < 8; t++)
      qf[t] = (short)f2b(b2f((u16)qraw[t]) * sc);
  }
  f32x4 o0 = {}, o1 = {};
  float psum[4] = {0.f, 0.f, 0.f, 0.f};
  for (int t = 0; t < 8; t++) {
    const int m0 = kc * 1024 + t * 128;
    __syncthreads();
#pragma unroll
    for (int cc = 0; cc < 2; cc++) {
      int ch = kb + 2 * cc;
      *(bf16x8*)&Ks[kr][(ch ^ (kr & 3)) * 8] =
          *(const bf16x8*)(qk + (size_t)(m0 + kr) * 256 + 128 + h * 32 + ch * 8);
    }
#pragma unroll
    for (int cc = 0; cc < 2; cc++) {
      int ch = vb + 8 * cc;
      *(bf16x8*)&Vt[vr][(ch ^ (vr & 15)) * 8] =
          *(const bf16x8*)(Vg + (size_t)(h * 32 + vr) * 4096 + m0 + ch * 8);
    }
    __syncthreads();
    f32x4 s[8];
#pragma unroll
    for (int jt = 0; jt < 8; jt++) {
      bf16x8 kf = *(const bf16x8*)&Ks[16 * jt + lr][(lq ^ (lr & 3)) * 8];
      f32x4 z = {};
      s[jt] = __builtin_amdgcn_mfma_f32_16x16x32_bf16(qf, kf, z, 0, 0, 0);
    }
#pragma unroll
    for (int jt = 0; jt < 8; jt++)
#pragma unroll
      for (int r = 0; r < 4; r++) {
        float p = __expf(s[jt][r]);
        psum[r] += p;
        int qrow = 16 * wv + lq * 4 + r;
        int ch = 2 * jt + (lr >> 3);
        Ps[qrow][(ch ^ (qrow & 15)) * 8 + (lr & 7)] = f2b(p);
      }
    __syncthreads();
#pragma unroll
    for (int kk = 0; kk < 4; kk++) {
      int prow = 16 * wv + lr;
      bf16x8 pf = *(const bf16x8*)&Ps[prow][((4 * kk + lq) ^ (lr & 15)) * 8];
      bf16x8 v0 = *(const bf16x8*)&Vt[lr][((4 * kk + lq) ^ (lr & 15)) * 8];
      bf16x8 v1 = *(const bf16x8*)&Vt[16 + lr][((4 * kk + lq) ^ (lr & 15)) * 8];
      o0 = __builtin_amdgcn_mfma_f32_16x16x32_bf16(pf, v0, o0, 0, 0, 0);
      o1 = __builtin_amdgcn_mfma_f32_16x16x32_bf16(pf, v1, o1, 0, 0, 0);
    }
  }
  const size_t ko = (size_t)kc * 524288;
  float* Lk = L + (size_t)kc * 16384;
#pragma unroll
  for (int r = 0; r < 4; r++) {
    int row = n0 + 16 * wv + lq * 4 + r;
    O[ko + (size_t)row * 128 + h * 32 + lr]      = o0[r];
    O[ko + (size_t)row * 128 + h * 32 + 16 + lr] = o1[r];
    float ps = psum[r];
    ps += __shfl_xor(ps, 1); ps += __shfl_xor(ps, 2);
    ps += __shfl_xor(ps, 4); ps += __shfl_xor(ps, 8);
    if (lr == 0) Lk[h * 4096 + row] = ps;
  }
}

// ------- r17: fused out_proj GEMM + residual + LayerNorm1 ------------------
__global__ __launch_bounds__(256) void oproj_ln(
    const float* __restrict__ Op, const float* __restrict__ Lp,
    const void* __restrict__ W, const void* __restrict__ bias,
    const void* __restrict__ x, const void* __restrict__ g,
    const void* __restrict__ bln, u16* __restrict__ y_bf,
    float* __restrict__ y_f32, const int* __restrict__ dflag)
{
  const int wbf = *dflag;
  __shared__ u16 As[16][128];
  __shared__ u16 Bs[128][128];   // re-used as float C[16][128] after MFMA
  const int tid = threadIdx.x;
  const int r0 = blockIdx.x * 16;
  {
    int r = tid >> 4, b = tid & 15;
    int hh = b >> 2;
    float Ls = Lp[hh * 4096 + r0 + r] + Lp[16384 + hh * 4096 + r0 + r]
             + Lp[32768 + hh * 4096 + r0 + r] + Lp[49152 + hh * 4096 + r0 + r];
    float iv = 1.0f / Ls;
    float a8[8] = {};
#pragma unroll
    for (int kc = 0; kc < 4; kc++) {
      const float* p = Op + (size_t)kc * 524288 + (size_t)(r0 + r) * 128 + b * 8;
      float4 q0 = *(const float4*)p, q1 = *(const float4*)(p + 4);
      a8[0] += q0.x; a8[1] += q0.y; a8[2] += q0.z; a8[3] += q0.w;
      a8[4] += q1.x; a8[5] += q1.y; a8[6] += q1.z; a8[7] += q1.w;
    }
    u16 t[8];
#pragma unroll
    for (int j = 0; j < 8; j++) t[j] = f2b(a8[j] * iv);
    *(bf16x8*)&As[r][(b ^ r) * 8] = *(bf16x8*)t;
  }
  {
    int o = tid >> 1, half = tid & 1;
#pragma unroll
    for (int bb8 = 0; bb8 < 8; bb8++) {
      int b = half * 8 + bb8;
      size_t off = (size_t)o * 128 + b * 8;
      if (wbf) {
        *(bf16x8*)&Bs[o][(b ^ (o & 15)) * 8] = *(const bf16x8*)((const u16*)W + off);
      } else {
        const float* pf = (const float*)W + off;
        float4 f0 = *(const float4*)pf, f1 = *(const float4*)(pf + 4);
        u16 t[8] = {f2b(f0.x), f2b(f0.y), f2b(f0.z), f2b(f0.w),
                    f2b(f1.x), f2b(f1.y), f2b(f1.z), f2b(f1.w)};
        *(bf16x8*)&Bs[o][(b ^ (o & 15)) * 8] = *(bf16x8*)t;
      }
    }
  }
  __syncthreads();
  const int wv = tid >> 6, l = tid & 63;
  const int lr = l & 15, lq = l >> 4;
  const int c0 = 32 * wv;
  f32x4 acc[2] = {};
#pragma unroll
  for (int kk = 0; kk < 4; kk++) {
    int bxs = ((4 * kk + lq) ^ lr) * 8;
    bf16x8 a0 = *(const bf16x8*)&As[lr][bxs];
    bf16x8 b0 = *(const bf16x8*)&Bs[c0 + lr][bxs];
    bf16x8 b1 = *(const bf16x8*)&Bs[c0 + 16 + lr][bxs];
    acc[0] = __builtin_amdgcn_mfma_f32_16x16x32_bf16(a0, b0, acc[0], 0, 0, 0);
    acc[1] = __builtin_amdgcn_mfma_f32_16x16x32_bf16(a0, b1, acc[1], 0, 0, 0);
  }
  __syncthreads();  // all LDS reads done; overlay C on Bs
  float* Cf = (float*)&Bs[0][0];
#pragma unroll
  for (int j = 0; j < 2; j++)
#pragma unroll
    for (int r = 0; r < 4; r++) {
      int row = lq * 4 + r, col = c0 + 16 * j + lr;
      float v = acc[j][r] + ld1(bias, col, wbf)
              + ld1(x, (size_t)(r0 + row) * 128 + col, wbf);
      Cf[row * 128 + col] = v;
    }
  __syncthreads();
#pragma unroll
  for (int it = 0; it < 4; it++) {
    int row = it * 4 + wv;
    float v0 = Cf[row * 128 + l], v1 = Cf[row * 128 + 64 + l];
    float s = v0 + v1, sq = v0 * v0 + v1 * v1;
    for (int off = 32; off; off >>= 1) { s += __shfl_down(s, off); sq += __shfl_down(sq, off); }
    s = __shfl(s, 0); sq = __shfl(sq, 0);
    float mu = s * (1.f / 128.f);
    float var = sq * (1.f / 128.f) - mu * mu;
    float rs = rsqrtf(var + 1e-5f);
    float o0 = (v0 - mu) * rs * ld1(g, l, wbf) + ld1(bln, l, wbf);
    float o1 = (v1 - mu) * rs * ld1(g, l + 64, wbf) + ld1(bln, l + 64, wbf);
    size_t i0 = (size_t)(r0 + row) * 128 + l;
    y_bf[i0] = f2b(o0); y_bf[i0 + 64] = f2b(o1);
    y_f32[i0] = o0; y_f32[i0 + 64] = o1;
  }
}

// ------- LayerNorm(A + sum_z R_z (+ rbias[col]))*g + b ---------------------
// float2-vectorized loads (adjacent cols per lane), ushort2 store.
__global__ __launch_bounds__(256) void ln_res(
    const float* __restrict__ A, const float* __restrict__ R,
    int nacc, const void* __restrict__ rbias,
    const void* __restrict__ g, const void* __restrict__ b,
    u16* __restrict__ out_bf, const int* __restrict__ dflag)
{
  const int wbf = *dflag;
  int row = blockIdx.x * 4 + (threadIdx.x >> 6);
  int lane = threadIdx.x & 63;
  size_t base = (size_t)row * 128 + 2 * lane;
  float2 av = *(const float2*)(A + base);
  float v0 = av.x, v1 = av.y;
  for (int z = 0; z < nacc; z++) {
    float2 rv = *(const float2*)(R + (size_t)z * 524288 + base);
    v0 += rv.x; v1 += rv.y;
  }
  if (rbias) { v0 += ld1(rbias, 2 * lane, wbf); v1 += ld1(rbias, 2 * lane + 1, wbf); }
  float s = v0 + v1, sq = v0 * v0 + v1 * v1;
  for (int off = 32; off; off >>= 1) { s += __shfl_down(s, off); sq += __shfl_down(sq, off); }
  s = __shfl(s, 0); sq = __shfl(sq, 0);
  float mu = s * (1.f / 128.f);
  float var = sq * (1.f / 128.f) - mu * mu;
  float rs = rsqrtf(var + 1e-5f);
  float r0 = (v0 - mu) * rs * ld1(g, 2 * lane, wbf) + ld1(b, 2 * lane, wbf);
  float r1 = (v1 - mu) * rs * ld1(g, 2 * lane + 1, wbf) + ld1(b, 2 * lane + 1, wbf);
  *(ushort2*)(out_bf + base) = make_ushort2(f2b(r0), f2b(r1));
}

// -------- gather: index-prefetch + 8x-unrolled edge loop (F=128/256) -------
// Per-sub FMA order identical to r19-r24 (bit-exact); eight loads in flight.
__global__ __launch_bounds__(256) void gcn_gather8(
    const u16* __restrict__ h, const int* __restrict__ deg,
    const int* __restrict__ csr, u16* __restrict__ out, int F)
{
  const int ft = F >> 3;           // 16 or 32
  const int tpn = ft << 1;         // 32 or 64
  const int node = blockIdx.x * (256 / tpn) + threadIdx.x / tpn;
  const int wl = threadIdx.x & 63;
  const int gl = threadIdx.x % tpn;
  const int sub = gl / ft;
  const int f = (gl % ft) * 8;
  const int gbase = wl - gl;
  int dn = deg[node]; if (dn > 128) dn = 128;
  float di = rsqrtf((float)(dn + 1));
  float a[8] = {};
  if (sub == 0) {
    bf16x8 hv = *(const bf16x8*)(h + (size_t)node * F + f);
#pragma unroll
    for (int j = 0; j < 8; j++) a[j] = di * b2f((u16)hv[j]);
  }
  const int e0 = node << 7;
  for (int base = 0; base < dn; base += tpn) {
    int lim = dn - base; if (lim > tpn) lim = tpn;
    int mi = 0;
    if (gl < lim) mi = csr[e0 + base + gl];
    float mds = rsqrtf((float)(deg[mi] + 1));
    int nj = (lim - sub + 1) >> 1;     // this sub's count
    int njmax = (lim + 1) >> 1;        // uniform trip count
    for (int jj = 0; jj < njmax; jj += 8) {
      int si[8]; float ds[8]; bool pr[8];
      bf16x8 sv[8];
#pragma unroll
      for (int k = 0; k < 8; k++) {
        si[k] = __shfl(mi, gbase + 2 * (jj + k) + sub);   // wraps if OOR; unused
        ds[k] = __shfl(mds, gbase + 2 * (jj + k) + sub);
        pr[k] = (jj + k < nj);
      }
#pragma unroll
      for (int k = 0; k < 8; k++)
        if (pr[k]) sv[k] = *(const bf16x8*)(h + (size_t)si[k] * F + f);
#pragma unroll
      for (int k = 0; k < 8; k++)
        if (pr[k]) {
#pragma unroll
          for (int j = 0; j < 8; j++) a[j] += ds[k] * b2f((u16)sv[k][j]);
        }
    }
  }
#pragma unroll
  for (int j = 0; j < 8; j++) a[j] += __shfl_xor(a[j], ft);
  if (sub) return;
  u16 t[8];
#pragma unroll
  for (int j = 0; j < 8; j++) t[j] = f2b(a[j] * di);
  *(bf16x8*)(out + (size_t)node * F + f) = *(bf16x8*)t;
}

// -------- final gather (F=64): serial order preserved, 4x-unrolled ---------
__global__ __launch_bounds__(256) void gcn_gather(
    const u16* __restrict__ h, const int* __restrict__ deg,
    const int* __restrict__ csr,
    const void* __restrict__ bias, void* __restrict__ out,
    int F, const int* __restrict__ dflag)
{
  const int wbf = *dflag;
  const int tpn = F >> 2;          // 16
  const int node = blockIdx.x * (256 / tpn) + threadIdx.x / tpn;
  const int wl = threadIdx.x & 63;
  const int gl = threadIdx.x % tpn;
  const int f = gl * 4;
  const int gbase = wl - gl;
  int dn = deg[node]; if (dn > 128) dn = 128;
  float di = rsqrtf((float)(dn + 1));
  ushort4 hv = *(const ushort4*)(h + (size_t)node * F + f);
  float a0 = di * b2f(hv.x), a1 = di * b2f(hv.y);
  float a2 = di * b2f(hv.z), a3 = di * b2f(hv.w);
  const int e0 = node << 7;
  for (int base = 0; base < dn; base += tpn) {
    int lim = dn - base; if (lim > tpn) lim = tpn;
    int mi = 0;
    if (gl < lim) mi = csr[e0 + base + gl];
    float mds = rsqrtf((float)(deg[mi] + 1));
    for (int j = 0; j < lim; j += 4) {
      int s0 = __shfl(mi, gbase + j);
      float d0 = __shfl(mds, gbase + j);
      int s1 = __shfl(mi, gbase + j + 1);   // wraps if OOR; unused
      float d1 = __shfl(mds, gbase + j + 1);
      int s2 = __shfl(mi, gbase + j + 2);
      float d2 = __shfl(mds, gbase + j + 2);
      int s3 = __shfl(mi, gbase + j + 3);
      float d3 = __shfl(mds, gbase + j + 3);
      bool p1 = (j + 1 < lim), p2 = (j + 2 < lim), p3 = (j + 3 < lim);
      ushort4 sv0 = *(const ushort4*)(h + (size_t)s0 * F + f);
      ushort4 sv1, sv2, sv3;
      if (p1) sv1 = *(const ushort4*)(h + (size_t)s1 * F + f);
      if (p2) sv2 = *(const ushort4*)(h + (size_t)s2 * F + f);
      if (p3) sv3 = *(const ushort4*)(h + (size_t)s3 * F + f);
      a0 += d0 * b2f(sv0.x); a1 += d0 * b2f(sv0.y);
      a2 += d0 * b2f(sv0.z); a3 += d0 * b2f(sv0.w);
      if (p1) {
        a0 += d1 * b2f(sv1.x); a1 += d1 * b2f(sv1.y);
        a2 += d1 * b2f(sv1.z); a3 += d1 * b2f(sv1.w);
      }
      if (p2) {
        a0 += d2 * b2f(sv2.x); a1 += d2 * b2f(sv2.y);
        a2 += d2 * b2f(sv2.z); a3 += d2 * b2f(sv2.w);
      }
      if (p3) {
        a0 += d3 * b2f(sv3.x); a1 += d3 * b2f(sv3.y);
        a2 += d3 * b2f(sv3.z); a3 += d3 * b2f(sv3.w);
      }
    }
  }
  float b0 = bias ? ld1(bias, f, wbf)     : 0.f;
  float b1 = bias ? ld1(bias, f + 1, wbf) : 0.f;
  float b2 = bias ? ld1(bias, f + 2, wbf) : 0.f;
  float b3 = bias ? ld1(bias, f + 3, wbf) : 0.f;
  float v0 = a0 * di + b0, v1 = a1 * di + b1;
  float v2 = a2 * di + b2, v3 = a3 * di + b3;
  size_t idx = (size_t)node * F + f;
  if (wbf) {
    *(ushort4*)((u16*)out + idx) = make_ushort4(f2b(v0), f2b(v1), f2b(v2), f2b(v3));
  } else {
    *(float4*)((float*)out + idx) = make_float4(v0, v1, v2, v3);
  }
}

extern "C" void kernel_launch(void* const* d_in, const int* in_sizes, int n_in,
                              void* d_out, int out_size, void* d_ws, size_t ws_size,
                              hipStream_t stream)
{
  const void* x          = d_in[0];
  const int*  edge       = (const int*)d_in[1];
  const void* in_proj_w  = d_in[2];
  const void* in_proj_b  = d_in[3];
  const void* out_proj_w = d_in[4];
  const void* out_proj_b = d_in[5];
  const void* ln1_g      = d_in[6];
  const void* ln1_b      = d_in[7];
  const void* ffn_w1     = d_in[8];
  const void* ffn_b1     = d_in[9];
  const void* ffn_w2     = d_in[10];
  const void* ffn_b2     = d_in[11];
  const void* ln2_g      = d_in[12];
  const void* ln2_b      = d_in[13];
  const void* g1w        = d_in[14];
  const void* g1b        = d_in[15];
  const void* g2w        = d_in[16];
  const void* g2b        = d_in[17];
  const void* g3w        = d_in[18];
  const void* g3b        = d_in[19];
  const int E = in_sizes[1] / 2;
  const int* esrc = edge;
  const int* edst = edge + E;

  char* wsb     = (char*)d_ws;
  u16*   qkQK   = (u16*)(wsb + 0);          // 2 MB
  u16*   Vg     = (u16*)(wsb + 2097152);    // 1 MB
  float* Op     = (float*)(wsb + 3145728);  // 4 x 2 MB partial O
  float* Lp     = (float*)(wsb + 11534336); // 4 x 64 KB partial L
  int*   cursor = (int*)(wsb + 11796480);   // 16 KB (zeroed by det_zero)
  int*   dflag  = (int*)(wsb + 11812864);   // 16 KB slot
  int*   csr    = (int*)(wsb + 11829248);   // 2 MB bucket [4096][128]
  float* y_f32  = (float*)(wsb + 13926400); // 2 MB
  u16*   y_bf   = (u16*)(wsb + 16023552);   // 1 MB
  u16*   z_bf   = (u16*)(wsb + 17072128);   // 1 MB
  u16*   az     = (u16*)(wsb + 18120704);   // 1 MB
  u16*   h1     = (u16*)(wsb + 19169280);   // 2 MB
  u16*   ah1    = (u16*)(wsb + 21266432);   // 2 MB
  u16*   h2     = (u16*)(wsb + 23363584);   // 2 MB
  u16*   t3     = (u16*)(wsb + 25460736);   // 512 KB
  u16*   ff1    = (u16*)(wsb + 25985024);   // 16 MB [4096][2048]
  float* ff2p   = (float*)(wsb + 42762240); // 4 x 2 MB partial

  det_zero<<<17, 256, 0, stream>>>(x, dflag, cursor);
  csr_inproj<<<512, 256, 0, stream>>>(x, in_proj_w, in_proj_b, qkQK, Vg, dflag,
      esrc, edst, cursor, csr, E);

  attn_part<<<dim3(64, 4, 4), 256, 0, stream>>>(qkQK, Vg, Op, Lp);
  oproj_ln<<<256, 256, 0, stream>>>(Op, Lp, out_proj_w, out_proj_b, x,
      ln1_g, ln1_b, y_bf, y_f32, dflag);
  // FFN (r21-proven): w1 (2048 blk), K-split w2 z=4 partial store, ln2
  gemm_mfma<<<dim3(32, 64), 256, 0, stream>>>(y_bf, ffn_w1, ffn_b1, ff1, nullptr,
      2048, 128, 128, 128, 0, 0, /*relu+bias*/ 1 | 8, dflag, nullptr);
  gemm_mfma<<<dim3(2, 64, 4), 256, 0, stream>>>(ff1, ffn_w2, nullptr, ff2p, nullptr,
      128, 2048, 2048, 2048, 0, 0, /*K-split partial*/ 32, dflag, nullptr);
  ln_res<<<1024, 256, 0, stream>>>(y_f32, ff2p, 4, ffn_b2, ln2_g, ln2_b,
      z_bf, dflag);

  // 3-layer GCN; aggregation commutes with the weight multiply
  gcn_gather8<<<512, 256, 0, stream>>>(z_bf, cursor, csr, az, 128);
  gemm_mfma<<<dim3(4, 64), 256, 0, stream>>>(az, g1w, g1b, h1, nullptr,
      256, 128, 128, 128, 0, 0, /*relu+bias*/ 1 | 8, dflag, nullptr);
  gcn_gather8<<<1024, 256, 0, stream>>>(h1, cursor, csr, ah1, 256);
  gemm_mfma<<<dim3(4, 64), 256, 0, stream>>>(ah1, g2w, g2b, h2, nullptr,
      256, 256, 256, 256, 0, 0, /*relu+bias*/ 1 | 8, dflag, nullptr);
  gemm_mfma<<<dim3(1, 64), 256, 0, stream>>>(h2, g3w, nullptr, t3, nullptr,
      64, 256, 256, 256, 0, 0, 0, dflag, nullptr);
  gcn_gather<<<256, 256, 0, stream>>>(t3, cursor, csr, g3b, d_out, 64, dflag);
}